// Round 9
// baseline (764.716 us; speedup 1.0000x reference)
//
#include <hip/hip_runtime.h>

#define FIELDS  100000
#define FACTORS 16
#define BATCH   1024
#define BT      8                      // batch rows per block
#define NCHUNK  16                     // field chunks (2 per XCD)
#define FPC     (FIELDS / NCHUNK)      // 6250 fields per chunk
#define BLOCK   256
#define TF      256                    // fields per tile
#define NFULL   (FPC / TF)             // 24 full tiles
#define NT      (NFULL + 1)            // +1 tail tile (106 valid fields)

typedef __attribute__((address_space(1))) const void gvoid;
typedef __attribute__((address_space(3))) void lvoid;

// Lane (qr = t&3, pg = t>>2): 4 consecutive fields (b128 LDS read), factor
// quarter qr. x0 staged via global_load_lds (2 instrs/wave/tile), 2-buffer,
// counted vmcnt (6 / 4, never 0 mid-loop). W read directly from L2 (no LDS).
// 2048 blocks, VGPR capped at 85 -> 6 waves/SIMD target.
__global__ __launch_bounds__(BLOCK, 6) void fm_partial(
    const int* __restrict__ x0, const float* __restrict__ W,
    float* __restrict__ ws)
{
    __shared__ __align__(16) int xbuf[2][BT][TF];   // 16 KB
    __shared__ float red[4][BT][17];                // 2.2 KB

    const int t     = threadIdx.x;
    const int bid   = blockIdx.x;
    const int rg    = bid >> 4;               // 0..127
    const int chunk = bid & (NCHUNK - 1);     // 0..15
    const int b0    = rg * BT;
    const int fbeg  = chunk * FPC;

    const int qr   = t & 3;                   // factor quarter
    const int pg   = t >> 2;                  // field group 0..63
    const int lane = t & 63;
    const int wv   = t >> 6;

    float acc[BT][4], qac[BT];
#pragma unroll
    for (int r = 0; r < BT; ++r) {
        qac[r] = 0.f;
#pragma unroll
        for (int j = 0; j < 4; ++j) acc[r][j] = 0.f;
    }

    const char* x0b = (const char*)x0;
    const char* Wb  = (const char*)W;
    const size_t XMAX = (size_t)BATCH * FIELDS * 4 - 16;

    // staging: wave wv stages rows {2wv, 2wv+1}; one 1KB wave-instr per row
    const int r0 = 2 * wv, r1 = 2 * wv + 1;
    const size_t sb0 = ((size_t)(b0 + r0) * FIELDS + fbeg) * 4 + (size_t)lane * 16;
    const size_t sb1 = ((size_t)(b0 + r1) * FIELDS + fbeg) * 4 + (size_t)lane * 16;
    char* const ldsb = (char*)&xbuf[0][0][0] + (size_t)lane * 16;

    auto STAGE = [&](int buf, int tile) {
        size_t s0 = sb0 + (size_t)tile * (TF * 4);
        size_t s1 = sb1 + (size_t)tile * (TF * 4);
        if (s0 > XMAX) s0 = XMAX;             // tail clamp; garbage masked later
        if (s1 > XMAX) s1 = XMAX;
        __builtin_amdgcn_global_load_lds((gvoid*)(x0b + s0),
            (lvoid*)(ldsb + buf * (BT * TF * 4) + r0 * (TF * 4)), 16, 0, 0);
        __builtin_amdgcn_global_load_lds((gvoid*)(x0b + s1),
            (lvoid*)(ldsb + buf * (BT * TF * 4) + r1 * (TF * 4)), 16, 0, 0);
    };

    STAGE(0, 0);

    for (int tl = 0; tl < NT; ++tl) {
        // ---- A) W loads for this tile (branchless clamped), L2-resident ----
        const int fb  = tl * TF + pg * 4;     // chunk-relative field of elem 0
        const int f0c = min(fb + 0, FPC - 1);
        const int f1c = min(fb + 1, FPC - 1);
        const int f2c = min(fb + 2, FPC - 1);
        const int f3c = min(fb + 3, FPC - 1);
        const unsigned qo = (unsigned)qr * 16u;
        const float4 w0 = *(const float4*)(Wb + (unsigned)(fbeg + f0c) * 64u + qo);
        const float4 w1 = *(const float4*)(Wb + (unsigned)(fbeg + f1c) * 64u + qo);
        const float4 w2 = *(const float4*)(Wb + (unsigned)(fbeg + f2c) * 64u + qo);
        const float4 w3 = *(const float4*)(Wb + (unsigned)(fbeg + f3c) * 64u + qo);

        // ---- B) stage next tile ----
        if (tl + 1 < NT) {
            STAGE((tl + 1) & 1, tl + 1);
            // outstanding: stage(tl)[2] + W[4] + stage(tl+1)[2] -> retire stage(tl)
            asm volatile("s_waitcnt vmcnt(6)" ::: "memory");
        } else {
            // outstanding: stage(tl)[2] + W[4] -> retire stage(tl), keep W
            asm volatile("s_waitcnt vmcnt(4)" ::: "memory");
        }
        __builtin_amdgcn_s_barrier();
        __builtin_amdgcn_sched_barrier(0);

        // ---- C) compute on tile tl ----
        const int buf = tl & 1;
        const float s0 = fmaf(w0.x, w0.x, fmaf(w0.y, w0.y, fmaf(w0.z, w0.z, w0.w * w0.w)));
        const float s1 = fmaf(w1.x, w1.x, fmaf(w1.y, w1.y, fmaf(w1.z, w1.z, w1.w * w1.w)));
        const float s2 = fmaf(w2.x, w2.x, fmaf(w2.y, w2.y, fmaf(w2.z, w2.z, w2.w * w2.w)));
        const float s3 = fmaf(w3.x, w3.x, fmaf(w3.y, w3.y, fmaf(w3.z, w3.z, w3.w * w3.w)));

        if (tl != NFULL) {                    // full tile (uniform branch)
#pragma unroll
            for (int r = 0; r < BT; ++r) {
                const int4 xv = *(const int4*)&xbuf[buf][r][pg * 4];
                const float m0 = (float)xv.x, m1 = (float)xv.y;
                const float m2 = (float)xv.z, m3 = (float)xv.w;
                qac[r]    = fmaf(m0, s0,   fmaf(m1, s1,   fmaf(m2, s2,   fmaf(m3, s3,   qac[r]))));
                acc[r][0] = fmaf(m0, w0.x, fmaf(m1, w1.x, fmaf(m2, w2.x, fmaf(m3, w3.x, acc[r][0]))));
                acc[r][1] = fmaf(m0, w0.y, fmaf(m1, w1.y, fmaf(m2, w2.y, fmaf(m3, w3.y, acc[r][1]))));
                acc[r][2] = fmaf(m0, w0.z, fmaf(m1, w1.z, fmaf(m2, w2.z, fmaf(m3, w3.z, acc[r][2]))));
                acc[r][3] = fmaf(m0, w0.w, fmaf(m1, w1.w, fmaf(m2, w2.w, fmaf(m3, w3.w, acc[r][3]))));
            }
        } else {                              // tail tile: mask invalid fields
            const bool v0 = (fb + 0) < FPC, v1 = (fb + 1) < FPC;
            const bool v2 = (fb + 2) < FPC, v3 = (fb + 3) < FPC;
#pragma unroll
            for (int r = 0; r < BT; ++r) {
                const int4 xv = *(const int4*)&xbuf[buf][r][pg * 4];
                const float m0 = v0 ? (float)xv.x : 0.f;
                const float m1 = v1 ? (float)xv.y : 0.f;
                const float m2 = v2 ? (float)xv.z : 0.f;
                const float m3 = v3 ? (float)xv.w : 0.f;
                qac[r]    = fmaf(m0, s0,   fmaf(m1, s1,   fmaf(m2, s2,   fmaf(m3, s3,   qac[r]))));
                acc[r][0] = fmaf(m0, w0.x, fmaf(m1, w1.x, fmaf(m2, w2.x, fmaf(m3, w3.x, acc[r][0]))));
                acc[r][1] = fmaf(m0, w0.y, fmaf(m1, w1.y, fmaf(m2, w2.y, fmaf(m3, w3.y, acc[r][1]))));
                acc[r][2] = fmaf(m0, w0.z, fmaf(m1, w1.z, fmaf(m2, w2.z, fmaf(m3, w3.z, acc[r][2]))));
                acc[r][3] = fmaf(m0, w0.w, fmaf(m1, w1.w, fmaf(m2, w2.w, fmaf(m3, w3.w, acc[r][3]))));
            }
        }
        __builtin_amdgcn_sched_barrier(0);    // LDS reads consumed above stay above
        __builtin_amdgcn_s_barrier();         // all waves done with buf
    }

    // ---- wave reduce ----
    // acc: sum lanes sharing qr (xor 4..32). qac: sum ALL 64 lanes — each lane
    // accumulated only its own quarter's ssq, so q is counted exactly once.
#pragma unroll
    for (int r = 0; r < BT; ++r) {
#pragma unroll
        for (int off = 4; off < 64; off <<= 1) {
            acc[r][0] += __shfl_xor(acc[r][0], off);
            acc[r][1] += __shfl_xor(acc[r][1], off);
            acc[r][2] += __shfl_xor(acc[r][2], off);
            acc[r][3] += __shfl_xor(acc[r][3], off);
        }
#pragma unroll
        for (int off = 1; off < 64; off <<= 1)
            qac[r] += __shfl_xor(qac[r], off);
    }

    __syncthreads();                          // red[] reuse safety
    if (lane < 4) {                           // lane l holds quarter l
#pragma unroll
        for (int r = 0; r < BT; ++r) {
#pragma unroll
            for (int j = 0; j < 4; ++j)
                red[wv][r][lane * 4 + j] = acc[r][j];
            if (lane == 0) red[wv][r][16] = qac[r];
        }
    }
    __syncthreads();
    if (t < BT * 17) {
        const int r = t / 17;
        const int j = t % 17;
        const float v = red[0][r][j] + red[1][r][j] + red[2][r][j] + red[3][r][j];
        ws[((size_t)(b0 + r) * NCHUNK + chunk) * 17 + j] = v;
    }
}

__global__ __launch_bounds__(BLOCK) void fm_final(
    const float* __restrict__ ws, float* __restrict__ out)
{
    const int b = blockIdx.x * BLOCK + threadIdx.x;
    if (b < BATCH) {
        const float* pbase = ws + (size_t)b * NCHUNK * 17;
        float s[17];
#pragma unroll
        for (int j = 0; j < 17; ++j) s[j] = 0.f;
#pragma unroll
        for (int c = 0; c < NCHUNK; ++c)
#pragma unroll
            for (int j = 0; j < 17; ++j) s[j] += pbase[c * 17 + j];
        float ss = 0.f;
#pragma unroll
        for (int k = 0; k < FACTORS; ++k) ss += s[k] * s[k];
        out[b] = 0.5f * (ss - s[16]);
    }
}

extern "C" void kernel_launch(void* const* d_in, const int* in_sizes, int n_in,
                              void* d_out, int out_size, void* d_ws, size_t ws_size,
                              hipStream_t stream)
{
    const int*   x0 = (const int*)d_in[0];
    const float* W  = (const float*)d_in[1];
    float* out = (float*)d_out;
    float* ws  = (float*)d_ws;   // [1024][16][17] floats = 1.1 MB, all slots written

    fm_partial<<<dim3((BATCH / BT) * NCHUNK), dim3(BLOCK), 0, stream>>>(x0, W, ws);
    fm_final<<<dim3((BATCH + BLOCK - 1) / BLOCK), dim3(BLOCK), 0, stream>>>(ws, out);
}

// Round 10
// 119.199 us; speedup vs baseline: 6.4154x; 6.4154x over previous
//
#include <hip/hip_runtime.h>

#define FIELDS  100000
#define FACTORS 16
#define BATCH   1024
#define BT      8                      // batch rows per block
#define NCHUNK  8                      // chunk == bid&7 -> XCD-pinned W slice
#define FPC     (FIELDS / NCHUNK)      // 12500
#define BLOCK   256
#define TF      256                    // fields per tile
#define NFULL   (FPC / TF)             // 48 full tiles (12288 fields, no clamps)
#define TAILPG  ((FPC - NFULL * TF) / 4)   // 53 (212 tail fields = 53*4 exactly)
#define NBUF    3

typedef __attribute__((address_space(1))) const void gvoid;
typedef __attribute__((address_space(3))) void lvoid;

// Lane (qr = t&3, pg = t>>2): 4 consecutive fields, factor quarter qr.
// Per wave-tile: 8 ds_read_b128 (x0, 4-dup broadcast = free 2-way), 4 global
// b128 W loads (L2-resident), 192 FMAs. x0 staged via global_load_lds into a
// 3-buffer pipeline; ONE barrier per tile (stage is issued after the barrier,
// so the barrier is both "tile ready" and the write-after-read guard for the
// buffer being restaged). Counted vmcnt = #VMEM-ops-after-S(tl) lower bound:
// hoisting W loads earlier only makes the count conservative, never unsafe.
__global__ __launch_bounds__(BLOCK, 4) void fm_partial(
    const int* __restrict__ x0, const float* __restrict__ W,
    float* __restrict__ ws)
{
    __shared__ __align__(16) int xbuf[NBUF][BT][TF];   // 24 KB
    __shared__ float red[4][BT][17];                   // 2.2 KB

    const int t     = threadIdx.x;
    const int bid   = blockIdx.x;
    const int rg    = bid >> 3;               // 0..127
    const int chunk = bid & (NCHUNK - 1);     // 0..7
    const int b0    = rg * BT;
    const int fbeg  = chunk * FPC;

    const int qr   = t & 3;                   // factor quarter
    const int pg   = t >> 2;                  // field group 0..63
    const int lane = t & 63;
    const int wv   = t >> 6;

    float acc[BT][4], qac[BT];
#pragma unroll
    for (int r = 0; r < BT; ++r) {
        qac[r] = 0.f;
#pragma unroll
        for (int j = 0; j < 4; ++j) acc[r][j] = 0.f;
    }

    const char* x0b = (const char*)x0;
    const char* Wb  = (const char*)W;

    // stage geometry: wave wv stages rows {2wv, 2wv+1}, 1 KB per wave-instr.
    // Max src = (1023*100000 + 87500 + 47*256)*4 + 63*16 = 409,599,136 < end:
    // always in-bounds, no clamps needed.
    const int r0 = 2 * wv, r1 = r0 + 1;
    const unsigned sb0 = ((unsigned)(b0 + r0) * FIELDS + (unsigned)fbeg) * 4u
                       + (unsigned)lane * 16u;
    const unsigned sb1 = sb0 + FIELDS * 4u;
    char* const l0 = (char*)&xbuf[0][r0][0] + lane * 16;
    char* const l1 = (char*)&xbuf[0][r1][0] + lane * 16;

#define STAGE(buf, tile) do {                                               \
        __builtin_amdgcn_global_load_lds(                                   \
            (gvoid*)(x0b + (sb0 + (unsigned)(tile) * (TF * 4u))),           \
            (lvoid*)(l0 + (buf) * (BT * TF * 4)), 16, 0, 0);                \
        __builtin_amdgcn_global_load_lds(                                   \
            (gvoid*)(x0b + (sb1 + (unsigned)(tile) * (TF * 4u))),           \
            (lvoid*)(l1 + (buf) * (BT * TF * 4)), 16, 0, 0);                \
    } while (0)

    // FM body: 4 W-rows (one quarter each) + 8 batch rows from int4 masks
#define FMTILE(BUFEXPR)                                                     \
    do {                                                                    \
        const float s0 = fmaf(w0.x, w0.x, fmaf(w0.y, w0.y, fmaf(w0.z, w0.z, w0.w * w0.w))); \
        const float s1 = fmaf(w1.x, w1.x, fmaf(w1.y, w1.y, fmaf(w1.z, w1.z, w1.w * w1.w))); \
        const float s2 = fmaf(w2.x, w2.x, fmaf(w2.y, w2.y, fmaf(w2.z, w2.z, w2.w * w2.w))); \
        const float s3 = fmaf(w3.x, w3.x, fmaf(w3.y, w3.y, fmaf(w3.z, w3.z, w3.w * w3.w))); \
        _Pragma("unroll")                                                   \
        for (int r = 0; r < BT; ++r) {                                      \
            const int4 xv = BUFEXPR;                                        \
            const float m0 = (float)xv.x, m1 = (float)xv.y;                 \
            const float m2 = (float)xv.z, m3 = (float)xv.w;                 \
            qac[r]    = fmaf(m0, s0,   fmaf(m1, s1,   fmaf(m2, s2,   fmaf(m3, s3,   qac[r])))); \
            acc[r][0] = fmaf(m0, w0.x, fmaf(m1, w1.x, fmaf(m2, w2.x, fmaf(m3, w3.x, acc[r][0])))); \
            acc[r][1] = fmaf(m0, w0.y, fmaf(m1, w1.y, fmaf(m2, w2.y, fmaf(m3, w3.y, acc[r][1])))); \
            acc[r][2] = fmaf(m0, w0.z, fmaf(m1, w1.z, fmaf(m2, w2.z, fmaf(m3, w3.z, acc[r][2])))); \
            acc[r][3] = fmaf(m0, w0.w, fmaf(m1, w1.w, fmaf(m2, w2.w, fmaf(m3, w3.w, acc[r][3])))); \
        }                                                                   \
    } while (0)

    STAGE(0, 0);
    STAGE(1, 1);

    const unsigned wq = (unsigned)qr * 16u;

    for (int tl = 0; tl < NFULL; ++tl) {
        // ---- W for this tile (issued pre-barrier: L2 latency overlaps it) ----
        const unsigned fB = (unsigned)(fbeg + tl * TF + pg * 4) * 64u + wq;
        const float4 w0 = *(const float4*)(Wb + fB);
        const float4 w1 = *(const float4*)(Wb + fB + 64u);
        const float4 w2 = *(const float4*)(Wb + fB + 128u);
        const float4 w3 = *(const float4*)(Wb + fB + 192u);

        // retire S(tl): N = ops issued after S(tl) in program order
        if      (tl == 0)         asm volatile("s_waitcnt vmcnt(6)"  ::: "memory");
        else if (tl < NFULL - 1)  asm volatile("s_waitcnt vmcnt(10)" ::: "memory");
        else                      asm volatile("s_waitcnt vmcnt(8)"  ::: "memory");
        __builtin_amdgcn_s_barrier();             // tile ready + buf-reuse guard
        __builtin_amdgcn_sched_barrier(0);

        if (tl + 2 < NFULL) STAGE((tl + 2) % NBUF, tl + 2);

        const int buf = tl % NBUF;
        FMTILE((*(const int4*)&xbuf[buf][r][pg * 4]));
        __builtin_amdgcn_sched_barrier(0);        // keep reads inside this phase
    }

    // ---- tail: 212 fields, per-lane-uniform validity (212 = 53*4) ----
    {
        const bool valid = (pg < TAILPG);
        const int  pgc   = valid ? pg : (TAILPG - 1);
        const unsigned fb = (unsigned)(fbeg + NFULL * TF + pgc * 4);
        const unsigned wB = fb * 64u + wq;
        float4 w0 = *(const float4*)(Wb + wB);
        float4 w1 = *(const float4*)(Wb + wB + 64u);
        float4 w2 = *(const float4*)(Wb + wB + 128u);
        float4 w3 = *(const float4*)(Wb + wB + 192u);
        if (!valid) {                             // zero W => zero contribution
            w0.x=w0.y=w0.z=w0.w=0.f; w1.x=w1.y=w1.z=w1.w=0.f;
            w2.x=w2.y=w2.z=w2.w=0.f; w3.x=w3.y=w3.z=w3.w=0.f;
        }
        FMTILE((*(const int4*)(x0b + ((unsigned)(b0 + r) * FIELDS + fb) * 4u)));
    }

    // ---- wave reduce ----
    // acc: sum lanes sharing qr (xor 4..32). qac: sum ALL 64 lanes — each lane
    // accumulated only its own quarter's ssq, so q is counted exactly once.
#pragma unroll
    for (int r = 0; r < BT; ++r) {
#pragma unroll
        for (int off = 4; off < 64; off <<= 1) {
            acc[r][0] += __shfl_xor(acc[r][0], off);
            acc[r][1] += __shfl_xor(acc[r][1], off);
            acc[r][2] += __shfl_xor(acc[r][2], off);
            acc[r][3] += __shfl_xor(acc[r][3], off);
        }
#pragma unroll
        for (int off = 1; off < 64; off <<= 1)
            qac[r] += __shfl_xor(qac[r], off);
    }

    if (lane < 4) {                               // lane l holds quarter l
#pragma unroll
        for (int r = 0; r < BT; ++r) {
#pragma unroll
            for (int j = 0; j < 4; ++j)
                red[wv][r][lane * 4 + j] = acc[r][j];
            if (lane == 0) red[wv][r][16] = qac[r];
        }
    }
    __syncthreads();
    if (t < BT * 17) {
        const int r = t / 17;
        const int j = t % 17;
        const float v = red[0][r][j] + red[1][r][j] + red[2][r][j] + red[3][r][j];
        ws[((size_t)(b0 + r) * NCHUNK + chunk) * 17 + j] = v;
    }
#undef STAGE
#undef FMTILE
}

__global__ __launch_bounds__(BLOCK) void fm_final(
    const float* __restrict__ ws, float* __restrict__ out)
{
    const int b = blockIdx.x * BLOCK + threadIdx.x;
    if (b < BATCH) {
        const float* pbase = ws + (size_t)b * NCHUNK * 17;
        float s[17];
#pragma unroll
        for (int j = 0; j < 17; ++j) s[j] = 0.f;
#pragma unroll
        for (int c = 0; c < NCHUNK; ++c)
#pragma unroll
            for (int j = 0; j < 17; ++j) s[j] += pbase[c * 17 + j];
        float ss = 0.f;
#pragma unroll
        for (int k = 0; k < FACTORS; ++k) ss += s[k] * s[k];
        out[b] = 0.5f * (ss - s[16]);
    }
}

extern "C" void kernel_launch(void* const* d_in, const int* in_sizes, int n_in,
                              void* d_out, int out_size, void* d_ws, size_t ws_size,
                              hipStream_t stream)
{
    const int*   x0 = (const int*)d_in[0];
    const float* W  = (const float*)d_in[1];
    float* out = (float*)d_out;
    float* ws  = (float*)d_ws;   // [1024][8][17] floats, every slot written

    fm_partial<<<dim3((BATCH / BT) * NCHUNK), dim3(BLOCK), 0, stream>>>(x0, W, ws);
    fm_final<<<dim3((BATCH + BLOCK - 1) / BLOCK), dim3(BLOCK), 0, stream>>>(ws, out);
}